// Round 17
// baseline (264.394 us; speedup 1.0000x reference)
//
#include <hip/hip_runtime.h>

#define EPSV 1e-8f
#define PW   34
#define NPIX 1024
#define NA   5
#define NOUT 17
#define NZC  150
#define NZP  75          // channel pairs
#define MAXS 8

typedef float v2f __attribute__((ext_vector_type(2)));
static __device__ __forceinline__ v2f fma2(v2f a, v2f b, v2f c) {
    return __builtin_elementwise_fma(a, b, c);
}

// ---- prep: repack R-conv weights into channel-pair float2 records ----------
// ws record p (c0=2p, c1=2p+1), j=0..23 float2:
//   j<18: {R1_w[c0*18+j], R1_w[c1*18+j]} | j==18: {R1_b[c0],R1_b[c1]}
//   j>18: a=j-19: {R2_w[a*150+c0], R2_w[a*150+c1]}
__global__ __launch_bounds__(256) void k_pack(
    const float* __restrict__ R1_w, const float* __restrict__ R1_b,
    const float* __restrict__ R2_w, float2* __restrict__ wpk)
{
    for (int i = threadIdx.x; i < NZP*24; i += 256) {
        const int p = i / 24, j = i % 24;
        const int c0 = 2*p, c1 = 2*p + 1;
        float v0, v1;
        if (j < 18)      { v0 = R1_w[c0*18 + j];        v1 = R1_w[c1*18 + j]; }
        else if (j == 18){ v0 = R1_b[c0];               v1 = R1_b[c1]; }
        else             { const int a = j - 19;
                           v0 = R2_w[a*NZC + c0];       v1 = R2_w[a*NZC + c1]; }
        wpk[i] = make_float2(v0, v1);
    }
}

// ============== shared body macro: everything except R-conv =================
#define COMMON_PROLOGUE                                                        \
    __shared__ float map0[PW*PW], map1[PW*PW], v_lds[PW*PW], b_lds[PW*PW];     \
    __shared__ float zc_w[NOUT*9], zc_b[NOUT];                                 \
    __shared__ float h_all[MAXS][NOUT], u_all[MAXS][NOUT], w_all[MAXS][NOUT];  \
    __shared__ float zo_lds[MAXS * NPIX];                                      \
    __shared__ float partials[16][6], sums[6];                                 \
    const int tid  = threadIdx.x;                                              \
    const int blk  = blockIdx.x;                                               \
    const int y    = tid >> 5, x = tid & 31;                                   \
    const int pidx = (y + 1) * PW + (x + 1);                                   \
    const int lane = tid & 63, wvid = tid >> 6;                                \
    const int S = step_p[0];                                                   \
    const int K = vik_p[0];                                                    \
    for (int i = tid; i < PW*PW; i += NPIX) {                                  \
        map0[i] = 0.f; map1[i] = 0.f; v_lds[i] = 0.f; b_lds[i] = 0.f;          \
    }                                                                          \
    __syncthreads();                                                           \
    map0[pidx]  = map_in[blk*2*NPIX + tid];                                    \
    map1[pidx]  = map_in[blk*2*NPIX + NPIX + tid];                             \
    b_lds[pidx] = b0[blk*NPIX + tid];                                          \
    if (tid < NOUT*9) {                                                        \
        const int o = tid / 9, k = tid % 9;                                    \
        float s = 0.f;                                                         \
        for (int c = 0; c < NZC; ++c) s += Z2_w[o*NZC + c] * Z1_w[c*9 + k];    \
        zc_w[tid] = s;                                                         \
    } else if (tid < NOUT*9 + NOUT) {                                          \
        const int o = tid - NOUT*9;                                            \
        float s = Z2_b[o];                                                     \
        for (int c = 0; c < NZC; ++c) s += Z2_w[o*NZC + c] * Z1_b[c];          \
        zc_b[o] = s;                                                           \
    }                                                                          \
    const int mt = tid - 256;                                                  \
    const int mT = mt / NOUT, mO = mt % NOUT;                                  \
    if (mt >= 0 && mt < S*NOUT) {                                              \
        const float* ob = obs_in + (blk*S + mT)*4;                             \
        float hh = O1_b[mO];                                                   \
        _Pragma("unroll")                                                      \
        for (int k = 0; k < 4; ++k) hh += ob[k] * O1_w[mO*4 + k];              \
        h_all[mT][mO] = tanhf(hh);                                             \
    }                                                                          \
    __syncthreads();                                                           \
    if (mt >= 0 && mt < S*NOUT) {                                              \
        float u = O3_b[mO];                                                    \
        _Pragma("unroll")                                                      \
        for (int j = 0; j < NOUT; ++j) u += h_all[mT][j] * O3_w[mO*NOUT + j];  \
        u_all[mT][mO] = u;                                                     \
    }                                                                          \
    __syncthreads();                                                           \
    if (mt >= 0 && mt < S*NOUT) {                                              \
        float mx = u_all[mT][0];                                               \
        _Pragma("unroll")                                                      \
        for (int j = 1; j < NOUT; ++j) mx = fmaxf(mx, u_all[mT][j]);           \
        float sm = 0.f;                                                        \
        _Pragma("unroll")                                                      \
        for (int j = 0; j < NOUT; ++j) sm += expf(u_all[mT][j] - mx);          \
        w_all[mT][mO] = expf(u_all[mT][mO] - mx) / sm;                         \
    }                                                                          \
    __syncthreads();                                                           \
    float m0[9], m1[9];                                                        \
    _Pragma("unroll")                                                          \
    for (int k = 0; k < 9; ++k) {                                              \
        const int off = (y + k/3)*PW + x + (k%3);                              \
        m0[k] = map0[off]; m1[k] = map1[off];                                  \
    }

#define COMMON_Z_PHASE                                                         \
    {                                                                          \
        float z[NOUT];                                                         \
        float zs = 0.f;                                                        \
        _Pragma("unroll")                                                      \
        for (int o = 0; o < NOUT; ++o) {                                       \
            float s = zc_b[o];                                                 \
            _Pragma("unroll")                                                  \
            for (int k = 0; k < 9; ++k) s += m0[k] * zc_w[o*9 + k];            \
            const float zz = 1.f / (1.f + expf(-s));                           \
            z[o] = zz; zs += zz;                                               \
        }                                                                      \
        const float zn = 1.f / (zs + EPSV);                                    \
        for (int t = 0; t < S; ++t) {                                          \
            float zo = 0.f;                                                    \
            _Pragma("unroll")                                                  \
            for (int o = 0; o < NOUT; ++o) zo += z[o] * w_all[t][o];           \
            zo_lds[t*NPIX + tid] = zo * zn;                                    \
        }                                                                      \
    }

#define COMMON_EPILOGUE                                                        \
    float q[NA];                                                               \
    _Pragma("unroll")                                                          \
    for (int a = 0; a < NA; ++a) q[a] = 0.f;                                   \
    for (int it = 0; it < K; ++it) {                                           \
        float n[9];                                                            \
        _Pragma("unroll")                                                      \
        for (int k = 0; k < 9; ++k) n[k] = v_lds[(y + k/3)*PW + x + (k%3)];    \
        float vmax = -3.4e38f;                                                 \
        _Pragma("unroll")                                                      \
        for (int a = 0; a < NA; ++a) {                                         \
            float s = Tv_b[a] + r[a];                                          \
            _Pragma("unroll")                                                  \
            for (int k = 0; k < 9; ++k) s += n[k] * Tv_w[a*9 + k];             \
            q[a] = s;                                                          \
            vmax = fmaxf(vmax, s);                                             \
        }                                                                      \
        __syncthreads();                                                       \
        v_lds[pidx] = vmax;                                                    \
        __syncthreads();                                                       \
    }                                                                          \
    for (int t = 0; t < S; ++t) {                                              \
        const int a_t = act_in[blk*S + t];                                     \
        float bp = Tb_b[a_t];                                                  \
        _Pragma("unroll")                                                      \
        for (int k = 0; k < 9; ++k)                                            \
            bp += b_lds[(y + k/3)*PW + x + (k%3)] * Tb_w[a_t*9 + k];           \
        const float bn = bp * zo_lds[t*NPIX + tid];                            \
        float v6[6];                                                           \
        v6[5] = bn;                                                            \
        _Pragma("unroll")                                                      \
        for (int a = 0; a < NA; ++a) v6[a] = q[a] * bn;                        \
        _Pragma("unroll")                                                      \
        for (int k = 0; k < 6; ++k) {                                          \
            float vv = v6[k];                                                  \
            for (int off = 32; off > 0; off >>= 1) vv += __shfl_down(vv, off); \
            v6[k] = vv;                                                        \
        }                                                                      \
        if (lane == 0) {                                                       \
            _Pragma("unroll")                                                  \
            for (int k = 0; k < 6; ++k) partials[wvid][k] = v6[k];             \
        }                                                                      \
        __syncthreads();                                                       \
        if (tid < 6) {                                                         \
            float s = 0.f;                                                     \
            for (int w2 = 0; w2 < 16; ++w2) s += partials[w2][tid];            \
            sums[tid] = s;                                                     \
        }                                                                      \
        __syncthreads();                                                       \
        const float inv = 1.f / (sums[5] + EPSV);                              \
        if (tid < NA) {                                                        \
            float oj = FL_b[tid];                                              \
            _Pragma("unroll")                                                  \
            for (int a = 0; a < NA; ++a) oj += (sums[a] * inv) * FL_w[tid*NA + a]; \
            out[(t*B + blk)*NA + tid] = oj;                                    \
        }                                                                      \
        b_lds[pidx] = bn * inv;                                                \
        __syncthreads();                                                       \
    }                                                                          \
    out[S*B*NA + blk*NPIX + tid] = b_lds[pidx];

#define PARAMS                                                                 \
    const float* __restrict__ map_in, const float* __restrict__ b0,            \
    const int*   __restrict__ act_in, const float* __restrict__ obs_in,        \
    const int*   __restrict__ step_p, const int*   __restrict__ vik_p,         \
    const float* __restrict__ Tb_w,  const float* __restrict__ Tb_b,           \
    const float* __restrict__ Tv_w,  const float* __restrict__ Tv_b,           \
    const float* __restrict__ Z1_w,  const float* __restrict__ Z1_b,           \
    const float* __restrict__ Z2_w,  const float* __restrict__ Z2_b,           \
    const float* __restrict__ O1_w,  const float* __restrict__ O1_b,           \
    const float* __restrict__ O3_w,  const float* __restrict__ O3_b,           \
    const float* __restrict__ R1_w,  const float* __restrict__ R1_b,           \
    const float* __restrict__ R2_w,  const float* __restrict__ R2_b,           \
    const float* __restrict__ FL_w,  const float* __restrict__ FL_b

// ===================== A: R12 verbatim (in-session anchor) ==================
__global__ __launch_bounds__(1024, 4) void vinA(
    PARAMS, float* __restrict__ out, int B)
{
    COMMON_PROLOGUE

    float rA_[NA], rB_[NA];
    #pragma unroll
    for (int a = 0; a < NA; ++a) { rA_[a] = R2_b[a]; rB_[a] = 0.f; }
    for (int c = 0; c < NZC; c += 2) {
        const float* w1a = R1_w + c*18;
        const float* w1b = w1a + 18;
        float s0 = R1_b[c], s1 = R1_b[c+1];
        #pragma unroll
        for (int k = 0; k < 9; ++k) { s0 += m0[k] * w1a[k];   s1 += m0[k] * w1b[k]; }
        #pragma unroll
        for (int k = 0; k < 9; ++k) { s0 += m1[k] * w1a[9+k]; s1 += m1[k] * w1b[9+k]; }
        s0 = fmaxf(s0, 0.f); s1 = fmaxf(s1, 0.f);
        #pragma unroll
        for (int a = 0; a < NA; ++a) {
            rA_[a] += R2_w[a*NZC + c]     * s0;
            rB_[a] += R2_w[a*NZC + c + 1] * s1;
        }
    }
    float r[NA];
    #pragma unroll
    for (int a = 0; a < NA; ++a) r[a] = rA_[a] + rB_[a];

    COMMON_Z_PHASE
    COMMON_EPILOGUE
}

// ============ B: packed-pair weights + v_pk_fma_f32 R-conv ==================
__global__ __launch_bounds__(1024, 4) void vinB(
    PARAMS, const float2* __restrict__ wpk, float* __restrict__ out, int B)
{
    COMMON_PROLOGUE
    COMMON_Z_PHASE          // Z first so m0/m1 can die before R-conv

    // hoisted tap splats (loop-invariant)
    v2f m0s[9], m1s[9];
    #pragma unroll
    for (int k = 0; k < 9; ++k) {
        m0s[k] = (v2f)(m0[k]);
        m1s[k] = (v2f)(m1[k]);
    }

    v2f r2[NA];
    #pragma unroll
    for (int a = 0; a < NA; ++a) r2[a] = (v2f)(0.f);
    const v2f* wp = (const v2f*)wpk;
    for (int p = 0; p < NZP; ++p) {
        const v2f* rec = wp + p*24;
        v2f s2 = rec[18];
        #pragma unroll
        for (int k = 0; k < 9; ++k) s2 = fma2(m0s[k], rec[k], s2);
        #pragma unroll
        for (int k = 0; k < 9; ++k) s2 = fma2(m1s[k], rec[9 + k], s2);
        s2 = __builtin_elementwise_max(s2, (v2f)(0.f));
        #pragma unroll
        for (int a = 0; a < NA; ++a) r2[a] = fma2(s2, rec[19 + a], r2[a]);
    }
    float r[NA];
    #pragma unroll
    for (int a = 0; a < NA; ++a) r[a] = R2_b[a] + r2[a].x + r2[a].y;

    COMMON_EPILOGUE
}

extern "C" void kernel_launch(void* const* d_in, const int* in_sizes, int n_in,
                              void* d_out, int out_size, void* d_ws, size_t ws_size,
                              hipStream_t stream)
{
    const float* map_in = (const float*)d_in[0];
    const float* b0     = (const float*)d_in[1];
    const int*   act_in = (const int*)  d_in[2];
    const float* obs_in = (const float*)d_in[3];
    const int*   step_p = (const int*)  d_in[5];
    const int*   vik_p  = (const int*)  d_in[6];
    const float* Tb_w = (const float*)d_in[7];
    const float* Tb_b = (const float*)d_in[8];
    const float* Tv_w = (const float*)d_in[9];
    const float* Tv_b = (const float*)d_in[10];
    const float* Z1_w = (const float*)d_in[11];
    const float* Z1_b = (const float*)d_in[12];
    const float* Z2_w = (const float*)d_in[13];
    const float* Z2_b = (const float*)d_in[14];
    const float* O1_w = (const float*)d_in[15];
    const float* O1_b = (const float*)d_in[16];
    const float* O3_w = (const float*)d_in[17];
    const float* O3_b = (const float*)d_in[18];
    const float* R1_w = (const float*)d_in[19];
    const float* R1_b = (const float*)d_in[20];
    const float* R2_w = (const float*)d_in[21];
    const float* R2_b = (const float*)d_in[22];
    const float* FL_w = (const float*)d_in[23];
    const float* FL_b = (const float*)d_in[24];

    const int B = in_sizes[1] / NPIX;

    float2* wpk = (float2*)d_ws;

    hipLaunchKernelGGL(k_pack, dim3(1), dim3(256), 0, stream,
        R1_w, R1_b, R2_w, wpk);

    hipLaunchKernelGGL(vinA, dim3(B), dim3(1024), 0, stream,
        map_in, b0, act_in, obs_in, step_p, vik_p,
        Tb_w, Tb_b, Tv_w, Tv_b, Z1_w, Z1_b, Z2_w, Z2_b,
        O1_w, O1_b, O3_w, O3_b, R1_w, R1_b, R2_w, R2_b,
        FL_w, FL_b, (float*)d_out, B);

    hipLaunchKernelGGL(vinB, dim3(B), dim3(1024), 0, stream,
        map_in, b0, act_in, obs_in, step_p, vik_p,
        Tb_w, Tb_b, Tv_w, Tv_b, Z1_w, Z1_b, Z2_w, Z2_b,
        O1_w, O1_b, O3_w, O3_b, R1_w, R1_b, R2_w, R2_b,
        FL_w, FL_b, wpk, (float*)d_out, B);
}